// Round 7
// baseline (192.922 us; speedup 1.0000x reference)
//
#include <hip/hip_runtime.h>
#include <hip/hip_bf16.h>

typedef __bf16 bf16_t;
typedef __bf16 bf16x8 __attribute__((ext_vector_type(8)));
typedef float  f32x4  __attribute__((ext_vector_type(4)));

#define B_ 8
#define T_ 2048
#define C_ 1024
#define H_ 64

#define MFMA16(a, b, c) __builtin_amdgcn_mfma_f32_16x16x32_bf16((a), (b), (c), 0, 0, 0)
// async global->LDS, 16B per lane; dest = wave-uniform base + lane*16 (linear)
#define GLL16(g, l) __builtin_amdgcn_global_load_lds( \
    (const __attribute__((address_space(1))) unsigned int*)(g), \
    (__attribute__((address_space(3))) unsigned int*)(l), 16, 0, 0)

// ---------------------------------------------------------------------------
// Kernel 1: W fp32 -> concatenated hi/lo bf16 [192][1024] (q|k|v rows).
// ---------------------------------------------------------------------------
__global__ __launch_bounds__(256) void wconv_kernel(
    const float* __restrict__ Wk, const float* __restrict__ Wq,
    const float* __restrict__ Wv,
    bf16_t* __restrict__ Wh, bf16_t* __restrict__ Wl)
{
    int i = blockIdx.x * 256 + threadIdx.x;
    int r = i >> 10;
    int c = i & 1023;
    float v;
    if (r < 64)       v = Wq[r * 1024 + c];
    else if (r < 128) v = Wk[(r - 64) * 1024 + c];
    else              v = Wv[(r - 128) * 1024 + c];
    bf16_t h = (bf16_t)v;
    Wh[i] = h;
    Wl[i] = (bf16_t)(v - (float)h);
}

// ---------------------------------------------------------------------------
// Kernel 2: QKV projection (R7: GLL staging, prefetch-order fix).
// R6 regression root cause: per-iter issue order was {x-prefetch, 6 GLLs,
// vmcnt(6)} -> the x HBM loads were OLDER than the 6 kept in flight, so every
// iteration exposed a ~900-cycle HBM round-trip before the barrier (~12 us).
// R7: issue x prefetch AFTER the GLLs and wait vmcnt(8): in-flight set is
// exactly {6 current GLLs + 2 newest x-loads}; the wait drains only the
// previous iteration's GLLs (+1-iter-old x, needed next iter anyway).
// LDS layout unchanged from R6: 24 lane-linear 1KB groups, conflict-free on
// both GLL writes and ds_read_b128 reads (SQ_LDS_BANK_CONFLICT measured 0).
// ---------------------------------------------------------------------------
__global__ __launch_bounds__(256, 2) void proj_kernel(
    const float*  __restrict__ x,
    const bf16_t* __restrict__ Wh, const bf16_t* __restrict__ Wl,
    bf16_t* __restrict__ qh, bf16_t* __restrict__ ql,
    bf16_t* __restrict__ kh, bf16_t* __restrict__ kl,
    bf16_t* __restrict__ vh)
{
    __shared__ bf16_t Wlds[2][24][512];    // 48 KB, double-buffered

    const int tid   = threadIdx.x;
    const int wid   = tid >> 6;
    const int lane  = tid & 63;
    const int quad  = lane >> 4;
    const int l16   = lane & 15;
    const int mhalf = wid >> 1;            // which 16-row group
    const int nhalf = wid & 1;             // which 96-col group
    const int g     = blockIdx.x * 32 + mhalf * 16 + l16;
    const float* xrow = x + (size_t)g * C_;

    // staging: wave w fills groups 6w..6w+5; per-lane source offset
    auto stage = [&](int k0, int bufi) {
        #pragma unroll
        for (int i = 0; i < 6; ++i) {
            int grp = wid * 6 + i;
            int mat = (grp >= 12);
            int nt  = mat ? grp - 12 : grp;
            const bf16_t* src = (mat ? Wl : Wh) + (nt * 16 + l16) * 1024 + k0 + quad * 8;
            GLL16(src, &Wlds[bufi][grp][0]);
        }
    };

    f32x4 x0a, x0b, x1a, x1b;
    x0a = *(const f32x4*)(xrow + quad * 8);
    x0b = *(const f32x4*)(xrow + quad * 8 + 4);
    x1a = *(const f32x4*)(xrow + 32 + quad * 8);
    x1b = *(const f32x4*)(xrow + 32 + quad * 8 + 4);
    stage(0, 0);

    f32x4 acc[6];
    #pragma unroll
    for (int i = 0; i < 6; ++i) acc[i] = (f32x4){0.f, 0.f, 0.f, 0.f};

    int buf = 0;
    for (int it = 0; it < 32; ++it) {
        // x register shift (no memory ops)
        float xv[8];
        *(f32x4*)xv       = x0a;
        *(f32x4*)(xv + 4) = x0b;
        x0a = x1a; x0b = x1b;

        // stage next K-tile FIRST, then x prefetch, then counted wait:
        // in-flight = 6 current GLLs + 2 x-loads = 8; drains prev-iter GLLs.
        if (it + 1 < 32) {
            stage((it + 1) * 32, buf ^ 1);
            if (it + 2 < 32) {
                x1a = *(const f32x4*)(xrow + (it + 2) * 32 + quad * 8);
                x1b = *(const f32x4*)(xrow + (it + 2) * 32 + quad * 8 + 4);
                asm volatile("s_waitcnt vmcnt(8)" ::: "memory");
            } else {
                asm volatile("s_waitcnt vmcnt(6)" ::: "memory");
            }
        } else {
            asm volatile("s_waitcnt vmcnt(0)" ::: "memory");
        }
        __syncthreads();                   // all waves' staging of buf landed

        bf16x8 ah, al;
        #pragma unroll
        for (int jj = 0; jj < 8; ++jj) {
            bf16_t h = (bf16_t)xv[jj];
            ah[jj] = h;
            al[jj] = (bf16_t)(xv[jj] - (float)h);
        }

        #pragma unroll
        for (int nt = 0; nt < 6; ++nt) {
            int grp = nhalf * 6 + nt;
            bf16x8 bh = *(const bf16x8*)(&Wlds[buf][grp][lane * 8]);
            bf16x8 bl = *(const bf16x8*)(&Wlds[buf][12 + grp][lane * 8]);
            acc[nt] = MFMA16(ah, bh, acc[nt]);
            acc[nt] = MFMA16(ah, bl, acc[nt]);
            acc[nt] = MFMA16(al, bh, acc[nt]);
        }

        __syncthreads();                   // done reading buf before re-stage
        buf ^= 1;
    }

    // epilogue: D layout col=lane&15, row=quad*4+reg
    const int rowbase = blockIdx.x * 32 + mhalf * 16 + quad * 4;
    for (int nt = 0; nt < 6; ++nt) {
        int n = (nhalf * 6 + nt) * 16 + l16;
        for (int rr = 0; rr < 4; ++rr) {
            int grow = rowbase + rr;
            int bb = grow >> 11, t = grow & 2047;
            float v  = acc[nt][rr];
            bf16_t h = (bf16_t)v;
            if (n < 64) {
                int off = (bb * T_ + t) * H_ + n;
                qh[off] = h; ql[off] = (bf16_t)(v - (float)h);
            } else if (n < 128) {
                int off = (bb * T_ + t) * H_ + (n - 64);
                kh[off] = h; kl[off] = (bf16_t)(v - (float)h);
            } else {
                vh[(bb * H_ + (n - 128)) * T_ + t] = h;
            }
        }
    }
}

// ---------------------------------------------------------------------------
// Kernel 3: attention (unchanged R4: block-cooperative LDS staging).
// ---------------------------------------------------------------------------
__global__ __launch_bounds__(512, 4) void attn_kernel(
    const bf16_t* __restrict__ qh, const bf16_t* __restrict__ ql,
    const bf16_t* __restrict__ kh, const bf16_t* __restrict__ kl,
    const bf16_t* __restrict__ vh,
    float* __restrict__ Oacc, float* __restrict__ lacc)
{
    __shared__ bf16_t KV[2][3][4096];     // [dbuf][kh|kl|v][64x64] = 48 KB
    __shared__ bf16_t Plds[8][16 * 72];   // per-wave P buffer, 18 KB

    const int tid  = threadIdx.x;
    const int wid  = tid >> 6;
    const int lane = tid & 63;
    const int quad = lane >> 4;
    const int l16  = lane & 15;

    const int b  = blockIdx.x & 7;         // XCD-aligned batch
    const int gp = (blockIdx.x >> 3) & 7;  // pair index
    const int s  = blockIdx.x >> 6;        // j-slice 0..7
    const int gA = gp, gB = 15 - gp;
    const int nA = 2 * gA + 2;             // j-steps of tile A (tile B: 34-nA)

    const int t_nt   = wid >> 1;
    const int t_kk   = wid & 1;
    const int t_l16  = tid & 15;
    const int t_quad = (tid >> 4) & 3;
    const int koff   = (t_nt * 16 + t_l16) * H_ + t_kk * 32 + t_quad * 8;
    const int voff   = (t_nt * 16 + t_l16) * T_ + t_kk * 32 + t_quad * 8;

    auto stage = [&](int j, int bufi) {
        const size_t kbase = (size_t)(b * T_ + 64 * j) * H_;
        GLL16(kh + kbase + koff, &KV[bufi][0][wid * 512]);
        GLL16(kl + kbase + koff, &KV[bufi][1][wid * 512]);
        GLL16(vh + (size_t)b * H_ * T_ + 64 * j + voff, &KV[bufi][2][wid * 512]);
    };

    f32x4  O[4];
    float  rowsum[4];
    bf16x8 aqh[2], aql[2];
    int    gcur = -1;

    auto flushO = [&]() {
        #pragma unroll
        for (int rr = 0; rr < 4; ++rr) {
            int trow = b * T_ + 128 * gcur + 16 * wid + quad * 4 + rr;
            #pragma unroll
            for (int ht = 0; ht < 4; ++ht)
                atomicAdd(Oacc + (size_t)trow * H_ + ht * 16 + l16, O[ht][rr]);
            float s_ = rowsum[rr];
            s_ += __shfl_xor(s_, 1, 64);
            s_ += __shfl_xor(s_, 2, 64);
            s_ += __shfl_xor(s_, 4, 64);
            s_ += __shfl_xor(s_, 8, 64);
            if (l16 == 0) atomicAdd(lacc + trow, s_);
        }
    };

    {
        int u0 = s;
        int j0 = (u0 < nA) ? u0 : (u0 - nA);
        stage(j0, 0);
    }

    int buf = 0;
    for (int u = s; u < 34; u += 8) {
        const int g = (u < nA) ? gA : gB;
        const int j = (u < nA) ? u : (u - nA);

        const int un = u + 8;
        if (un < 34) {
            int jn = (un < nA) ? un : (un - nA);
            stage(jn, buf ^ 1);
            asm volatile("s_waitcnt vmcnt(3)" ::: "memory");
        } else {
            asm volatile("s_waitcnt vmcnt(0)" ::: "memory");
        }
        __syncthreads();

        if (g != gcur) {
            if (gcur >= 0) flushO();
            gcur = g;
            const size_t qoff = (size_t)(b * T_ + 128 * g + 16 * wid + l16) * H_;
            #pragma unroll
            for (int kk = 0; kk < 2; ++kk) {
                aqh[kk] = *(const bf16x8*)(qh + qoff + kk * 32 + quad * 8);
                aql[kk] = *(const bf16x8*)(ql + qoff + kk * 32 + quad * 8);
            }
            #pragma unroll
            for (int i = 0; i < 4; ++i) { O[i] = (f32x4){0.f,0.f,0.f,0.f}; rowsum[i] = 0.f; }
        }

        const bf16_t* Kh = KV[buf][0];
        const bf16_t* Kl = KV[buf][1];
        f32x4 S[4];
        #pragma unroll
        for (int i = 0; i < 4; ++i) S[i] = (f32x4){0.f,0.f,0.f,0.f};
        #pragma unroll
        for (int nt = 0; nt < 4; ++nt) {
            #pragma unroll
            for (int kk = 0; kk < 2; ++kk) {
                bf16x8 bh = *(const bf16x8*)(Kh + (nt * 2 + kk) * 512 + lane * 8);
                bf16x8 bl = *(const bf16x8*)(Kl + (nt * 2 + kk) * 512 + lane * 8);
                S[nt] = MFMA16(aqh[kk], bh, S[nt]);
                S[nt] = MFMA16(aqh[kk], bl, S[nt]);
                S[nt] = MFMA16(aql[kk], bh, S[nt]);
            }
        }

        bf16_t* Pw = Plds[wid];
        const int rloc = 128 * g + 16 * wid + quad * 4;
        #pragma unroll
        for (int nt = 0; nt < 4; ++nt) {
            int colt = 64 * j + nt * 16 + l16;
            #pragma unroll
            for (int rr = 0; rr < 4; ++rr) {
                float pv = (colt <= rloc + rr)
                         ? __expf(fmaf(S[nt][rr], 0.125f, -20.0f)) : 0.f;
                rowsum[rr] += pv;
                Pw[(quad * 4 + rr) * 72 + nt * 16 + l16] = (bf16_t)pv;
            }
        }

        bf16x8 ap0 = *(const bf16x8*)(Pw + l16 * 72 + quad * 8);
        bf16x8 ap1 = *(const bf16x8*)(Pw + l16 * 72 + 32 + quad * 8);

        const bf16_t* Vt = KV[buf][2];
        #pragma unroll
        for (int ht = 0; ht < 4; ++ht) {
            bf16x8 bv0 = *(const bf16x8*)(Vt + (ht * 2 + 0) * 512 + lane * 8);
            bf16x8 bv1 = *(const bf16x8*)(Vt + (ht * 2 + 1) * 512 + lane * 8);
            O[ht] = MFMA16(ap0, bv0, O[ht]);
            O[ht] = MFMA16(ap1, bv1, O[ht]);
        }

        __syncthreads();
        buf ^= 1;
    }
    if (gcur >= 0) flushO();
}

// ---------------------------------------------------------------------------
// Kernel 4: out = Oacc / lacc
// ---------------------------------------------------------------------------
__global__ __launch_bounds__(256) void div_kernel(
    const float* __restrict__ Oacc, const float* __restrict__ lacc,
    float* __restrict__ out)
{
    int i = blockIdx.x * 256 + threadIdx.x;          // f32x4 index, 262144 total
    f32x4 o   = ((const f32x4*)Oacc)[i];
    float inv = 1.0f / lacc[i >> 4];
    ((f32x4*)out)[i] = o * inv;
}

// ---------------------------------------------------------------------------
extern "C" void kernel_launch(void* const* d_in, const int* in_sizes, int n_in,
                              void* d_out, int out_size, void* d_ws, size_t ws_size,
                              hipStream_t stream)
{
    const float* x  = (const float*)d_in[0];
    const float* Wk = (const float*)d_in[1];
    const float* Wq = (const float*)d_in[2];
    const float* Wv = (const float*)d_in[3];
    float* out = (float*)d_out;

    char* ws = (char*)d_ws;
    const size_t WSZ = 192 * 1024 * sizeof(bf16_t);            // 393216
    const size_t QSZ = (size_t)B_ * T_ * H_ * sizeof(bf16_t);  // 2097152
    bf16_t* Wh   = (bf16_t*)(ws);
    bf16_t* Wl   = (bf16_t*)(ws + WSZ);
    bf16_t* qh   = (bf16_t*)(ws + 2 * WSZ);
    bf16_t* ql   = (bf16_t*)(ws + 2 * WSZ + 1 * QSZ);
    bf16_t* kh   = (bf16_t*)(ws + 2 * WSZ + 2 * QSZ);
    bf16_t* kl   = (bf16_t*)(ws + 2 * WSZ + 3 * QSZ);
    bf16_t* vh   = (bf16_t*)(ws + 2 * WSZ + 4 * QSZ);
    float*  Oacc = (float*)(ws + 2 * WSZ + 5 * QSZ);           // 4 MB
    float*  lacc = (float*)(ws + 2 * WSZ + 5 * QSZ + (size_t)B_ * T_ * H_ * 4);

    // zero Oacc (4 MB) + lacc (64 KB), contiguous
    hipMemsetAsync(Oacc, 0, (size_t)B_ * T_ * H_ * 4 + (size_t)B_ * T_ * 4, stream);
    hipLaunchKernelGGL(wconv_kernel, dim3(768), dim3(256), 0, stream, Wk, Wq, Wv, Wh, Wl);
    hipLaunchKernelGGL(proj_kernel, dim3(512), dim3(256), 0, stream,
                       x, Wh, Wl, qh, ql, kh, kl, vh);
    hipLaunchKernelGGL(attn_kernel, dim3(512), dim3(512), 0, stream,
                       qh, ql, kh, kl, vh, Oacc, lacc);
    hipLaunchKernelGGL(div_kernel, dim3(1024), dim3(256), 0, stream, Oacc, lacc, out);
}

// Round 8
// 184.681 us; speedup vs baseline: 1.0446x; 1.0446x over previous
//
#include <hip/hip_runtime.h>
#include <hip/hip_bf16.h>

typedef __bf16 bf16_t;
typedef __bf16 bf16x8 __attribute__((ext_vector_type(8)));
typedef float  f32x4  __attribute__((ext_vector_type(4)));

#define B_ 8
#define T_ 2048
#define C_ 1024
#define H_ 64

#define MFMA16(a, b, c) __builtin_amdgcn_mfma_f32_16x16x32_bf16((a), (b), (c), 0, 0, 0)
// async global->LDS, 16B per lane; dest = wave-uniform base + lane*16 (linear)
#define GLL16(g, l) __builtin_amdgcn_global_load_lds( \
    (const __attribute__((address_space(1))) unsigned int*)(g), \
    (__attribute__((address_space(3))) unsigned int*)(l), 16, 0, 0)

// ---------------------------------------------------------------------------
// Kernel 1: W fp32 -> hi/lo bf16 [192][1024] (q|k|v rows) + zero Oacc/lacc.
// 1040 blocks x 256: zero slice = exactly 266240 f32x4 (4 MB Oacc + 64 KB
// lacc); blocks < 768 also convert W.  Folds the old hipMemsetAsync launch.
// ---------------------------------------------------------------------------
__global__ __launch_bounds__(256) void wconv_kernel(
    const float* __restrict__ Wk, const float* __restrict__ Wq,
    const float* __restrict__ Wv,
    bf16_t* __restrict__ Wh, bf16_t* __restrict__ Wl,
    f32x4* __restrict__ zero_dst)
{
    int i = blockIdx.x * 256 + threadIdx.x;
    zero_dst[i] = (f32x4){0.f, 0.f, 0.f, 0.f};      // 1040*256 = 266240 exact
    if (blockIdx.x < 768) {
        int r = i >> 10;
        int c = i & 1023;
        float v;
        if (r < 64)       v = Wq[r * 1024 + c];
        else if (r < 128) v = Wk[(r - 64) * 1024 + c];
        else              v = Wv[(r - 128) * 1024 + c];
        bf16_t h = (bf16_t)v;
        Wh[i] = h;
        Wl[i] = (bf16_t)(v - (float)h);
    }
}

// ---------------------------------------------------------------------------
// Kernel 2: QKV projection (R8: fatter barrier intervals).
// R7 post-mortem: time ~ n_barriers x exposed-latency (5.9K cyc/iter vs 1.5K
// of work; all pipes idle).  R8: M-tile 64, K-step 64 -> 256 blocks x 512
// threads (8 waves), 16 iters x 2 barriers (was 32x2), 2x compute per
// interval, W L2 re-read halved (197 MB).  LDS 2 x 48 groups x 1KB (96 KB)
// GLL-staged double buffer, conflict-free layout per ksub (proven: 0
// conflicts).  Counted vmcnt(10) = {6 GLLs + 4 x-loads} in flight.
// Wave (mhalf,nhalf): rows 16*mhalf..+15, cols nhalf*96..+95, acc[6].
// ---------------------------------------------------------------------------
__global__ __launch_bounds__(512, 2) void proj_kernel(
    const float*  __restrict__ x,
    const bf16_t* __restrict__ Wh, const bf16_t* __restrict__ Wl,
    bf16_t* __restrict__ qh, bf16_t* __restrict__ ql,
    bf16_t* __restrict__ kh, bf16_t* __restrict__ kl,
    bf16_t* __restrict__ vh)
{
    __shared__ bf16_t Wlds[2][48][512];    // 96 KB, double-buffered

    const int tid   = threadIdx.x;
    const int wid   = tid >> 6;            // 0..7
    const int lane  = tid & 63;
    const int quad  = lane >> 4;
    const int l16   = lane & 15;
    const int mhalf = wid >> 1;            // 16-row group 0..3
    const int nhalf = wid & 1;             // 96-col group
    const int g     = blockIdx.x * 64 + mhalf * 16 + l16;
    const float* xrow = x + (size_t)g * C_;

    // staging: wave w fills groups 6w..6w+5 of 48; grp = ksub*24 + mat*12 + nt
    auto stage = [&](int k0, int bufi) {
        #pragma unroll
        for (int i = 0; i < 6; ++i) {
            int grp  = wid * 6 + i;
            int ksub = (grp >= 24);
            int rem  = grp - ksub * 24;
            int mat  = (rem >= 12);
            int nt   = rem - mat * 12;
            const bf16_t* src = (mat ? Wl : Wh)
                + (nt * 16 + l16) * 1024 + k0 + ksub * 32 + quad * 8;
            GLL16(src, &Wlds[bufi][grp][0]);
        }
    };
    // x chunk it = k cols [it*64, it*64+64): per lane 2 ksubs x 8 floats
    auto loadx = [&](int it, f32x4* d) {
        #pragma unroll
        for (int ks = 0; ks < 2; ++ks) {
            d[ks * 2]     = *(const f32x4*)(xrow + it * 64 + ks * 32 + quad * 8);
            d[ks * 2 + 1] = *(const f32x4*)(xrow + it * 64 + ks * 32 + quad * 8 + 4);
        }
    };

    stage(0, 0);
    f32x4 x0[4], x1[4];
    loadx(0, x0);
    loadx(1, x1);

    f32x4 acc[6];
    #pragma unroll
    for (int i = 0; i < 6; ++i) acc[i] = (f32x4){0.f, 0.f, 0.f, 0.f};

    int buf = 0;
    for (int it = 0; it < 16; ++it) {
        float xv[16];
        *(f32x4*)(xv)      = x0[0];
        *(f32x4*)(xv + 4)  = x0[1];
        *(f32x4*)(xv + 8)  = x0[2];
        *(f32x4*)(xv + 12) = x0[3];
        #pragma unroll
        for (int i = 0; i < 4; ++i) x0[i] = x1[i];

        if (it + 1 < 16) {
            stage((it + 1) * 64, buf ^ 1);
            if (it + 2 < 16) {
                loadx(it + 2, x1);
                asm volatile("s_waitcnt vmcnt(10)" ::: "memory");
            } else {
                asm volatile("s_waitcnt vmcnt(6)" ::: "memory");
            }
        } else {
            asm volatile("s_waitcnt vmcnt(0)" ::: "memory");
        }
        __syncthreads();                   // all waves' staging of buf landed

        #pragma unroll
        for (int ks = 0; ks < 2; ++ks) {
            bf16x8 ah, al;
            #pragma unroll
            for (int jj = 0; jj < 8; ++jj) {
                float  xf = xv[ks * 8 + jj];
                bf16_t h  = (bf16_t)xf;
                ah[jj] = h;
                al[jj] = (bf16_t)(xf - (float)h);
            }
            #pragma unroll
            for (int nt = 0; nt < 6; ++nt) {
                int gi = ks * 24 + nhalf * 6 + nt;
                bf16x8 bh = *(const bf16x8*)(&Wlds[buf][gi][lane * 8]);
                bf16x8 bl = *(const bf16x8*)(&Wlds[buf][gi + 12][lane * 8]);
                acc[nt] = MFMA16(ah, bh, acc[nt]);
                acc[nt] = MFMA16(ah, bl, acc[nt]);
                acc[nt] = MFMA16(al, bh, acc[nt]);
            }
        }

        __syncthreads();                   // done reading buf before re-stage
        buf ^= 1;
    }

    // epilogue: D layout col=lane&15, row=quad*4+reg
    const int rowbase = blockIdx.x * 64 + mhalf * 16 + quad * 4;
    for (int nt = 0; nt < 6; ++nt) {
        int n = (nhalf * 6 + nt) * 16 + l16;
        for (int rr = 0; rr < 4; ++rr) {
            int grow = rowbase + rr;
            int bb = grow >> 11, t = grow & 2047;
            float v  = acc[nt][rr];
            bf16_t h = (bf16_t)v;
            if (n < 64) {
                int off = (bb * T_ + t) * H_ + n;
                qh[off] = h; ql[off] = (bf16_t)(v - (float)h);
            } else if (n < 128) {
                int off = (bb * T_ + t) * H_ + (n - 64);
                kh[off] = h; kl[off] = (bf16_t)(v - (float)h);
            } else {
                vh[(bb * H_ + (n - 128)) * T_ + t] = h;
            }
        }
    }
}

// ---------------------------------------------------------------------------
// Kernel 3: attention (unchanged R4: block-cooperative LDS staging).
// ---------------------------------------------------------------------------
__global__ __launch_bounds__(512, 4) void attn_kernel(
    const bf16_t* __restrict__ qh, const bf16_t* __restrict__ ql,
    const bf16_t* __restrict__ kh, const bf16_t* __restrict__ kl,
    const bf16_t* __restrict__ vh,
    float* __restrict__ Oacc, float* __restrict__ lacc)
{
    __shared__ bf16_t KV[2][3][4096];     // [dbuf][kh|kl|v][64x64] = 48 KB
    __shared__ bf16_t Plds[8][16 * 72];   // per-wave P buffer, 18 KB

    const int tid  = threadIdx.x;
    const int wid  = tid >> 6;
    const int lane = tid & 63;
    const int quad = lane >> 4;
    const int l16  = lane & 15;

    const int b  = blockIdx.x & 7;         // XCD-aligned batch
    const int gp = (blockIdx.x >> 3) & 7;  // pair index
    const int s  = blockIdx.x >> 6;        // j-slice 0..7
    const int gA = gp, gB = 15 - gp;
    const int nA = 2 * gA + 2;             // j-steps of tile A (tile B: 34-nA)

    const int t_nt   = wid >> 1;
    const int t_kk   = wid & 1;
    const int t_l16  = tid & 15;
    const int t_quad = (tid >> 4) & 3;
    const int koff   = (t_nt * 16 + t_l16) * H_ + t_kk * 32 + t_quad * 8;
    const int voff   = (t_nt * 16 + t_l16) * T_ + t_kk * 32 + t_quad * 8;

    auto stage = [&](int j, int bufi) {
        const size_t kbase = (size_t)(b * T_ + 64 * j) * H_;
        GLL16(kh + kbase + koff, &KV[bufi][0][wid * 512]);
        GLL16(kl + kbase + koff, &KV[bufi][1][wid * 512]);
        GLL16(vh + (size_t)b * H_ * T_ + 64 * j + voff, &KV[bufi][2][wid * 512]);
    };

    f32x4  O[4];
    float  rowsum[4];
    bf16x8 aqh[2], aql[2];
    int    gcur = -1;

    auto flushO = [&]() {
        #pragma unroll
        for (int rr = 0; rr < 4; ++rr) {
            int trow = b * T_ + 128 * gcur + 16 * wid + quad * 4 + rr;
            #pragma unroll
            for (int ht = 0; ht < 4; ++ht)
                atomicAdd(Oacc + (size_t)trow * H_ + ht * 16 + l16, O[ht][rr]);
            float s_ = rowsum[rr];
            s_ += __shfl_xor(s_, 1, 64);
            s_ += __shfl_xor(s_, 2, 64);
            s_ += __shfl_xor(s_, 4, 64);
            s_ += __shfl_xor(s_, 8, 64);
            if (l16 == 0) atomicAdd(lacc + trow, s_);
        }
    };

    {
        int u0 = s;
        int j0 = (u0 < nA) ? u0 : (u0 - nA);
        stage(j0, 0);
    }

    int buf = 0;
    for (int u = s; u < 34; u += 8) {
        const int g = (u < nA) ? gA : gB;
        const int j = (u < nA) ? u : (u - nA);

        const int un = u + 8;
        if (un < 34) {
            int jn = (un < nA) ? un : (un - nA);
            stage(jn, buf ^ 1);
            asm volatile("s_waitcnt vmcnt(3)" ::: "memory");
        } else {
            asm volatile("s_waitcnt vmcnt(0)" ::: "memory");
        }
        __syncthreads();

        if (g != gcur) {
            if (gcur >= 0) flushO();
            gcur = g;
            const size_t qoff = (size_t)(b * T_ + 128 * g + 16 * wid + l16) * H_;
            #pragma unroll
            for (int kk = 0; kk < 2; ++kk) {
                aqh[kk] = *(const bf16x8*)(qh + qoff + kk * 32 + quad * 8);
                aql[kk] = *(const bf16x8*)(ql + qoff + kk * 32 + quad * 8);
            }
            #pragma unroll
            for (int i = 0; i < 4; ++i) { O[i] = (f32x4){0.f,0.f,0.f,0.f}; rowsum[i] = 0.f; }
        }

        const bf16_t* Kh = KV[buf][0];
        const bf16_t* Kl = KV[buf][1];
        f32x4 S[4];
        #pragma unroll
        for (int i = 0; i < 4; ++i) S[i] = (f32x4){0.f,0.f,0.f,0.f};
        #pragma unroll
        for (int nt = 0; nt < 4; ++nt) {
            #pragma unroll
            for (int kk = 0; kk < 2; ++kk) {
                bf16x8 bh = *(const bf16x8*)(Kh + (nt * 2 + kk) * 512 + lane * 8);
                bf16x8 bl = *(const bf16x8*)(Kl + (nt * 2 + kk) * 512 + lane * 8);
                S[nt] = MFMA16(aqh[kk], bh, S[nt]);
                S[nt] = MFMA16(aqh[kk], bl, S[nt]);
                S[nt] = MFMA16(aql[kk], bh, S[nt]);
            }
        }

        bf16_t* Pw = Plds[wid];
        const int rloc = 128 * g + 16 * wid + quad * 4;
        #pragma unroll
        for (int nt = 0; nt < 4; ++nt) {
            int colt = 64 * j + nt * 16 + l16;
            #pragma unroll
            for (int rr = 0; rr < 4; ++rr) {
                float pv = (colt <= rloc + rr)
                         ? __expf(fmaf(S[nt][rr], 0.125f, -20.0f)) : 0.f;
                rowsum[rr] += pv;
                Pw[(quad * 4 + rr) * 72 + nt * 16 + l16] = (bf16_t)pv;
            }
        }

        bf16x8 ap0 = *(const bf16x8*)(Pw + l16 * 72 + quad * 8);
        bf16x8 ap1 = *(const bf16x8*)(Pw + l16 * 72 + 32 + quad * 8);

        const bf16_t* Vt = KV[buf][2];
        #pragma unroll
        for (int ht = 0; ht < 4; ++ht) {
            bf16x8 bv0 = *(const bf16x8*)(Vt + (ht * 2 + 0) * 512 + lane * 8);
            bf16x8 bv1 = *(const bf16x8*)(Vt + (ht * 2 + 1) * 512 + lane * 8);
            O[ht] = MFMA16(ap0, bv0, O[ht]);
            O[ht] = MFMA16(ap1, bv1, O[ht]);
        }

        __syncthreads();
        buf ^= 1;
    }
    if (gcur >= 0) flushO();
}

// ---------------------------------------------------------------------------
// Kernel 4: out = Oacc / lacc
// ---------------------------------------------------------------------------
__global__ __launch_bounds__(256) void div_kernel(
    const float* __restrict__ Oacc, const float* __restrict__ lacc,
    float* __restrict__ out)
{
    int i = blockIdx.x * 256 + threadIdx.x;          // f32x4 index, 262144 total
    f32x4 o   = ((const f32x4*)Oacc)[i];
    float inv = 1.0f / lacc[i >> 4];
    ((f32x4*)out)[i] = o * inv;
}

// ---------------------------------------------------------------------------
extern "C" void kernel_launch(void* const* d_in, const int* in_sizes, int n_in,
                              void* d_out, int out_size, void* d_ws, size_t ws_size,
                              hipStream_t stream)
{
    const float* x  = (const float*)d_in[0];
    const float* Wk = (const float*)d_in[1];
    const float* Wq = (const float*)d_in[2];
    const float* Wv = (const float*)d_in[3];
    float* out = (float*)d_out;

    char* ws = (char*)d_ws;
    const size_t WSZ = 192 * 1024 * sizeof(bf16_t);            // 393216
    const size_t QSZ = (size_t)B_ * T_ * H_ * sizeof(bf16_t);  // 2097152
    bf16_t* Wh   = (bf16_t*)(ws);
    bf16_t* Wl   = (bf16_t*)(ws + WSZ);
    bf16_t* qh   = (bf16_t*)(ws + 2 * WSZ);
    bf16_t* ql   = (bf16_t*)(ws + 2 * WSZ + 1 * QSZ);
    bf16_t* kh   = (bf16_t*)(ws + 2 * WSZ + 2 * QSZ);
    bf16_t* kl   = (bf16_t*)(ws + 2 * WSZ + 3 * QSZ);
    bf16_t* vh   = (bf16_t*)(ws + 2 * WSZ + 4 * QSZ);
    float*  Oacc = (float*)(ws + 2 * WSZ + 5 * QSZ);           // 4 MB
    float*  lacc = (float*)(ws + 2 * WSZ + 5 * QSZ + (size_t)B_ * T_ * H_ * 4);

    hipLaunchKernelGGL(wconv_kernel, dim3(1040), dim3(256), 0, stream,
                       Wk, Wq, Wv, Wh, Wl, (f32x4*)Oacc);
    hipLaunchKernelGGL(proj_kernel, dim3(256), dim3(512), 0, stream,
                       x, Wh, Wl, qh, ql, kh, kl, vh);
    hipLaunchKernelGGL(attn_kernel, dim3(512), dim3(512), 0, stream,
                       qh, ql, kh, kl, vh, Oacc, lacc);
    hipLaunchKernelGGL(div_kernel, dim3(1024), dim3(256), 0, stream, Oacc, lacc, out);
}

// Round 9
// 169.922 us; speedup vs baseline: 1.1354x; 1.0869x over previous
//
#include <hip/hip_runtime.h>
#include <hip/hip_bf16.h>

typedef __bf16 bf16_t;
typedef __bf16 bf16x8 __attribute__((ext_vector_type(8)));
typedef float  f32x4  __attribute__((ext_vector_type(4)));

#define B_ 8
#define T_ 2048
#define C_ 1024
#define H_ 64

#define MFMA16(a, b, c) __builtin_amdgcn_mfma_f32_16x16x32_bf16((a), (b), (c), 0, 0, 0)
// async global->LDS, 16B per lane; dest = wave-uniform base + lane*16 (linear)
#define GLL16(g, l) __builtin_amdgcn_global_load_lds( \
    (const __attribute__((address_space(1))) unsigned int*)(g), \
    (__attribute__((address_space(3))) unsigned int*)(l), 16, 0, 0)
// RAW barrier: __syncthreads() is lowered by hipcc as s_waitcnt vmcnt(0)
// lgkmcnt(0) + s_barrier, which synchronously drains the in-flight prefetch
// GLLs every iteration (defeats counted vmcnt).  Raw s_barrier + our explicit
// counted s_waitcnt keeps next-tile loads in flight across the barrier
// (AITER/HK pattern).  "memory" clobber stops LDS op reordering across it.
#define SBAR() asm volatile("s_barrier" ::: "memory")

// ---------------------------------------------------------------------------
// Kernel 1: W fp32 -> hi/lo bf16 [192][1024] (q|k|v rows) + zero Oacc/lacc.
// ---------------------------------------------------------------------------
__global__ __launch_bounds__(256) void wconv_kernel(
    const float* __restrict__ Wk, const float* __restrict__ Wq,
    const float* __restrict__ Wv,
    bf16_t* __restrict__ Wh, bf16_t* __restrict__ Wl,
    f32x4* __restrict__ zero_dst)
{
    int i = blockIdx.x * 256 + threadIdx.x;
    zero_dst[i] = (f32x4){0.f, 0.f, 0.f, 0.f};      // 1040*256 = 266240 exact
    if (blockIdx.x < 768) {
        int r = i >> 10;
        int c = i & 1023;
        float v;
        if (r < 64)       v = Wq[r * 1024 + c];
        else if (r < 128) v = Wk[(r - 64) * 1024 + c];
        else              v = Wv[(r - 128) * 1024 + c];
        bf16_t h = (bf16_t)v;
        Wh[i] = h;
        Wl[i] = (bf16_t)(v - (float)h);
    }
}

// ---------------------------------------------------------------------------
// Kernel 2: QKV projection (R9: raw barriers -> counted vmcnt finally live).
// Structure identical to R8 (M-tile 64, K-step 64, 256 blocks x 512 thr,
// 96 KB dbuf GLL staging, conflict-free layout).  Only sync changed:
// __syncthreads -> SBAR().  vmcnt(10) = {6 next GLLs + 4 x-loads} stay in
// flight across the barrier and drain one full compute interval later.
// ---------------------------------------------------------------------------
__global__ __launch_bounds__(512, 2) void proj_kernel(
    const float*  __restrict__ x,
    const bf16_t* __restrict__ Wh, const bf16_t* __restrict__ Wl,
    bf16_t* __restrict__ qh, bf16_t* __restrict__ ql,
    bf16_t* __restrict__ kh, bf16_t* __restrict__ kl,
    bf16_t* __restrict__ vh)
{
    __shared__ bf16_t Wlds[2][48][512];    // 96 KB, double-buffered

    const int tid   = threadIdx.x;
    const int wid   = tid >> 6;            // 0..7
    const int lane  = tid & 63;
    const int quad  = lane >> 4;
    const int l16   = lane & 15;
    const int mhalf = wid >> 1;            // 16-row group 0..3
    const int nhalf = wid & 1;             // 96-col group
    const int g     = blockIdx.x * 64 + mhalf * 16 + l16;
    const float* xrow = x + (size_t)g * C_;

    // staging: wave w fills groups 6w..6w+5 of 48; grp = ksub*24 + mat*12 + nt
    auto stage = [&](int k0, int bufi) {
        #pragma unroll
        for (int i = 0; i < 6; ++i) {
            int grp  = wid * 6 + i;
            int ksub = (grp >= 24);
            int rem  = grp - ksub * 24;
            int mat  = (rem >= 12);
            int nt   = rem - mat * 12;
            const bf16_t* src = (mat ? Wl : Wh)
                + (nt * 16 + l16) * 1024 + k0 + ksub * 32 + quad * 8;
            GLL16(src, &Wlds[bufi][grp][0]);
        }
    };
    // x chunk it = k cols [it*64, it*64+64): per lane 2 ksubs x 8 floats
    auto loadx = [&](int it, f32x4* d) {
        #pragma unroll
        for (int ks = 0; ks < 2; ++ks) {
            d[ks * 2]     = *(const f32x4*)(xrow + it * 64 + ks * 32 + quad * 8);
            d[ks * 2 + 1] = *(const f32x4*)(xrow + it * 64 + ks * 32 + quad * 8 + 4);
        }
    };

    stage(0, 0);
    f32x4 x0[4], x1[4];
    loadx(0, x0);
    loadx(1, x1);

    f32x4 acc[6];
    #pragma unroll
    for (int i = 0; i < 6; ++i) acc[i] = (f32x4){0.f, 0.f, 0.f, 0.f};

    int buf = 0;
    for (int it = 0; it < 16; ++it) {
        float xv[16];
        *(f32x4*)(xv)      = x0[0];
        *(f32x4*)(xv + 4)  = x0[1];
        *(f32x4*)(xv + 8)  = x0[2];
        *(f32x4*)(xv + 12) = x0[3];
        #pragma unroll
        for (int i = 0; i < 4; ++i) x0[i] = x1[i];

        if (it + 1 < 16) {
            stage((it + 1) * 64, buf ^ 1);
            if (it + 2 < 16) {
                loadx(it + 2, x1);
                asm volatile("s_waitcnt vmcnt(10)" ::: "memory");
            } else {
                asm volatile("s_waitcnt vmcnt(6)" ::: "memory");
            }
        } else {
            asm volatile("s_waitcnt vmcnt(0)" ::: "memory");
        }
        SBAR();                            // raw: prefetch stays in flight

        #pragma unroll
        for (int ks = 0; ks < 2; ++ks) {
            bf16x8 ah, al;
            #pragma unroll
            for (int jj = 0; jj < 8; ++jj) {
                float  xf = xv[ks * 8 + jj];
                bf16_t h  = (bf16_t)xf;
                ah[jj] = h;
                al[jj] = (bf16_t)(xf - (float)h);
            }
            #pragma unroll
            for (int nt = 0; nt < 6; ++nt) {
                int gi = ks * 24 + nhalf * 6 + nt;
                bf16x8 bh = *(const bf16x8*)(&Wlds[buf][gi][lane * 8]);
                bf16x8 bl = *(const bf16x8*)(&Wlds[buf][gi + 12][lane * 8]);
                acc[nt] = MFMA16(ah, bh, acc[nt]);
                acc[nt] = MFMA16(ah, bl, acc[nt]);
                acc[nt] = MFMA16(al, bh, acc[nt]);
            }
        }

        SBAR();                            // protect buf before re-staging
        buf ^= 1;
    }

    // epilogue: D layout col=lane&15, row=quad*4+reg
    const int rowbase = blockIdx.x * 64 + mhalf * 16 + quad * 4;
    for (int nt = 0; nt < 6; ++nt) {
        int n = (nhalf * 6 + nt) * 16 + l16;
        for (int rr = 0; rr < 4; ++rr) {
            int grow = rowbase + rr;
            int bb = grow >> 11, t = grow & 2047;
            float v  = acc[nt][rr];
            bf16_t h = (bf16_t)v;
            if (n < 64) {
                int off = (bb * T_ + t) * H_ + n;
                qh[off] = h; ql[off] = (bf16_t)(v - (float)h);
            } else if (n < 128) {
                int off = (bb * T_ + t) * H_ + (n - 64);
                kh[off] = h; kl[off] = (bf16_t)(v - (float)h);
            } else {
                vh[(bb * H_ + (n - 128)) * T_ + t] = h;
            }
        }
    }
}

// ---------------------------------------------------------------------------
// Kernel 3: attention (R4 structure; R9: raw barriers, counted vmcnt live).
// ---------------------------------------------------------------------------
__global__ __launch_bounds__(512, 4) void attn_kernel(
    const bf16_t* __restrict__ qh, const bf16_t* __restrict__ ql,
    const bf16_t* __restrict__ kh, const bf16_t* __restrict__ kl,
    const bf16_t* __restrict__ vh,
    float* __restrict__ Oacc, float* __restrict__ lacc)
{
    __shared__ bf16_t KV[2][3][4096];     // [dbuf][kh|kl|v][64x64] = 48 KB
    __shared__ bf16_t Plds[8][16 * 72];   // per-wave P buffer, 18 KB

    const int tid  = threadIdx.x;
    const int wid  = tid >> 6;
    const int lane = tid & 63;
    const int quad = lane >> 4;
    const int l16  = lane & 15;

    const int b  = blockIdx.x & 7;         // XCD-aligned batch
    const int gp = (blockIdx.x >> 3) & 7;  // pair index
    const int s  = blockIdx.x >> 6;        // j-slice 0..7
    const int gA = gp, gB = 15 - gp;
    const int nA = 2 * gA + 2;             // j-steps of tile A (tile B: 34-nA)

    const int t_nt   = wid >> 1;
    const int t_kk   = wid & 1;
    const int t_l16  = tid & 15;
    const int t_quad = (tid >> 4) & 3;
    const int koff   = (t_nt * 16 + t_l16) * H_ + t_kk * 32 + t_quad * 8;
    const int voff   = (t_nt * 16 + t_l16) * T_ + t_kk * 32 + t_quad * 8;

    auto stage = [&](int j, int bufi) {
        const size_t kbase = (size_t)(b * T_ + 64 * j) * H_;
        GLL16(kh + kbase + koff, &KV[bufi][0][wid * 512]);
        GLL16(kl + kbase + koff, &KV[bufi][1][wid * 512]);
        GLL16(vh + (size_t)b * H_ * T_ + 64 * j + voff, &KV[bufi][2][wid * 512]);
    };

    f32x4  O[4];
    float  rowsum[4];
    bf16x8 aqh[2], aql[2];
    int    gcur = -1;

    auto flushO = [&]() {
        #pragma unroll
        for (int rr = 0; rr < 4; ++rr) {
            int trow = b * T_ + 128 * gcur + 16 * wid + quad * 4 + rr;
            #pragma unroll
            for (int ht = 0; ht < 4; ++ht)
                atomicAdd(Oacc + (size_t)trow * H_ + ht * 16 + l16, O[ht][rr]);
            float s_ = rowsum[rr];
            s_ += __shfl_xor(s_, 1, 64);
            s_ += __shfl_xor(s_, 2, 64);
            s_ += __shfl_xor(s_, 4, 64);
            s_ += __shfl_xor(s_, 8, 64);
            if (l16 == 0) atomicAdd(lacc + trow, s_);
        }
    };

    {
        int u0 = s;
        int j0 = (u0 < nA) ? u0 : (u0 - nA);
        stage(j0, 0);
    }

    int buf = 0;
    for (int u = s; u < 34; u += 8) {
        const int g = (u < nA) ? gA : gB;
        const int j = (u < nA) ? u : (u - nA);

        const int un = u + 8;
        if (un < 34) {
            int jn = (un < nA) ? un : (un - nA);
            stage(jn, buf ^ 1);
            asm volatile("s_waitcnt vmcnt(3)" ::: "memory");
        } else {
            asm volatile("s_waitcnt vmcnt(0)" ::: "memory");
        }
        SBAR();                            // raw: next K/V stays in flight

        if (g != gcur) {
            if (gcur >= 0) flushO();
            gcur = g;
            const size_t qoff = (size_t)(b * T_ + 128 * g + 16 * wid + l16) * H_;
            #pragma unroll
            for (int kk = 0; kk < 2; ++kk) {
                aqh[kk] = *(const bf16x8*)(qh + qoff + kk * 32 + quad * 8);
                aql[kk] = *(const bf16x8*)(ql + qoff + kk * 32 + quad * 8);
            }
            #pragma unroll
            for (int i = 0; i < 4; ++i) { O[i] = (f32x4){0.f,0.f,0.f,0.f}; rowsum[i] = 0.f; }
        }

        const bf16_t* Kh = KV[buf][0];
        const bf16_t* Kl = KV[buf][1];
        f32x4 S[4];
        #pragma unroll
        for (int i = 0; i < 4; ++i) S[i] = (f32x4){0.f,0.f,0.f,0.f};
        #pragma unroll
        for (int nt = 0; nt < 4; ++nt) {
            #pragma unroll
            for (int kk = 0; kk < 2; ++kk) {
                bf16x8 bh = *(const bf16x8*)(Kh + (nt * 2 + kk) * 512 + lane * 8);
                bf16x8 bl = *(const bf16x8*)(Kl + (nt * 2 + kk) * 512 + lane * 8);
                S[nt] = MFMA16(aqh[kk], bh, S[nt]);
                S[nt] = MFMA16(aqh[kk], bl, S[nt]);
                S[nt] = MFMA16(aql[kk], bh, S[nt]);
            }
        }

        bf16_t* Pw = Plds[wid];
        const int rloc = 128 * g + 16 * wid + quad * 4;
        #pragma unroll
        for (int nt = 0; nt < 4; ++nt) {
            int colt = 64 * j + nt * 16 + l16;
            #pragma unroll
            for (int rr = 0; rr < 4; ++rr) {
                float pv = (colt <= rloc + rr)
                         ? __expf(fmaf(S[nt][rr], 0.125f, -20.0f)) : 0.f;
                rowsum[rr] += pv;
                Pw[(quad * 4 + rr) * 72 + nt * 16 + l16] = (bf16_t)pv;
            }
        }

        bf16x8 ap0 = *(const bf16x8*)(Pw + l16 * 72 + quad * 8);
        bf16x8 ap1 = *(const bf16x8*)(Pw + l16 * 72 + 32 + quad * 8);

        const bf16_t* Vt = KV[buf][2];
        #pragma unroll
        for (int ht = 0; ht < 4; ++ht) {
            bf16x8 bv0 = *(const bf16x8*)(Vt + (ht * 2 + 0) * 512 + lane * 8);
            bf16x8 bv1 = *(const bf16x8*)(Vt + (ht * 2 + 1) * 512 + lane * 8);
            O[ht] = MFMA16(ap0, bv0, O[ht]);
            O[ht] = MFMA16(ap1, bv1, O[ht]);
        }

        SBAR();                            // done reading buf before re-stage
        buf ^= 1;
    }
    if (gcur >= 0) flushO();
}

// ---------------------------------------------------------------------------
// Kernel 4: out = Oacc / lacc
// ---------------------------------------------------------------------------
__global__ __launch_bounds__(256) void div_kernel(
    const float* __restrict__ Oacc, const float* __restrict__ lacc,
    float* __restrict__ out)
{
    int i = blockIdx.x * 256 + threadIdx.x;          // f32x4 index, 262144 total
    f32x4 o   = ((const f32x4*)Oacc)[i];
    float inv = 1.0f / lacc[i >> 4];
    ((f32x4*)out)[i] = o * inv;
}

// ---------------------------------------------------------------------------
extern "C" void kernel_launch(void* const* d_in, const int* in_sizes, int n_in,
                              void* d_out, int out_size, void* d_ws, size_t ws_size,
                              hipStream_t stream)
{
    const float* x  = (const float*)d_in[0];
    const float* Wk = (const float*)d_in[1];
    const float* Wq = (const float*)d_in[2];
    const float* Wv = (const float*)d_in[3];
    float* out = (float*)d_out;

    char* ws = (char*)d_ws;
    const size_t WSZ = 192 * 1024 * sizeof(bf16_t);            // 393216
    const size_t QSZ = (size_t)B_ * T_ * H_ * sizeof(bf16_t);  // 2097152
    bf16_t* Wh   = (bf16_t*)(ws);
    bf16_t* Wl   = (bf16_t*)(ws + WSZ);
    bf16_t* qh   = (bf16_t*)(ws + 2 * WSZ);
    bf16_t* ql   = (bf16_t*)(ws + 2 * WSZ + 1 * QSZ);
    bf16_t* kh   = (bf16_t*)(ws + 2 * WSZ + 2 * QSZ);
    bf16_t* kl   = (bf16_t*)(ws + 2 * WSZ + 3 * QSZ);
    bf16_t* vh   = (bf16_t*)(ws + 2 * WSZ + 4 * QSZ);
    float*  Oacc = (float*)(ws + 2 * WSZ + 5 * QSZ);           // 4 MB
    float*  lacc = (float*)(ws + 2 * WSZ + 5 * QSZ + (size_t)B_ * T_ * H_ * 4);

    hipLaunchKernelGGL(wconv_kernel, dim3(1040), dim3(256), 0, stream,
                       Wk, Wq, Wv, Wh, Wl, (f32x4*)Oacc);
    hipLaunchKernelGGL(proj_kernel, dim3(256), dim3(512), 0, stream,
                       x, Wh, Wl, qh, ql, kh, kl, vh);
    hipLaunchKernelGGL(attn_kernel, dim3(512), dim3(512), 0, stream,
                       qh, ql, kh, kl, vh, Oacc, lacc);
    hipLaunchKernelGGL(div_kernel, dim3(1024), dim3(256), 0, stream, Oacc, lacc, out);
}